// Round 1
// baseline (615.783 us; speedup 1.0000x reference)
//
#include <hip/hip_runtime.h>
#include <math.h>

// NeuralCache: idx = hash(trunc(pos*10)) & 4095; feat = emb[idx]; x = [feat, normal] (19)
// h1 = relu(x@W1+b1) (64); h2 = relu(h1@W2+b2) (64); out = sigmoid(h2@W3+b3) (3)
//
// Round 1: correctness-first fp32 VALU kernel, one thread per point.
// Weights are wave-uniform -> indexed with compile-time offsets off uniform
// pointers so the compiler emits scalar loads (constant cache), j-major
// accumulators so the scalar loads are contiguous (dwordx16-able).

__global__ __launch_bounds__(256) void nc_kernel(
    const float* __restrict__ pos, const float* __restrict__ nrm,
    const float* __restrict__ emb, const float* __restrict__ W1,
    const float* __restrict__ b1, const float* __restrict__ W2,
    const float* __restrict__ b2, const float* __restrict__ W3,
    const float* __restrict__ b3, float* __restrict__ out, int n)
{
    int i = blockIdx.x * blockDim.x + threadIdx.x;
    if (i >= n) return;

    // ---- hash index (low-12-bit exact in 32-bit arithmetic) ----
    float px = pos[3*i+0], py = pos[3*i+1], pz = pos[3*i+2];
    int sx = (int)(px * 10.0f);   // trunc toward zero == astype(int64)
    int sy = (int)(py * 10.0f);
    int sz = (int)(pz * 10.0f);
    unsigned h = ((unsigned)sx * 73856093u)
               ^ ((unsigned)sy * 19349663u)
               ^ ((unsigned)sz * 83492791u);
    int idx = (int)(h & 4095u);   // floor-mod 4096 == low 12 bits

    // ---- gather + concat ----
    float x[19];
    #pragma unroll
    for (int k = 0; k < 16; ++k) x[k] = emb[idx*16 + k];
    x[16] = nrm[3*i+0]; x[17] = nrm[3*i+1]; x[18] = nrm[3*i+2];

    // ---- layer 1: 19 -> 64 (k-outer so weight reads are contiguous) ----
    float a[64];
    #pragma unroll
    for (int j = 0; j < 64; ++j) a[j] = b1[j];
    #pragma unroll
    for (int k = 0; k < 19; ++k) {
        float xv = x[k];
        #pragma unroll
        for (int j = 0; j < 64; ++j) a[j] = fmaf(xv, W1[k*64 + j], a[j]);
    }
    #pragma unroll
    for (int j = 0; j < 64; ++j) a[j] = fmaxf(a[j], 0.0f);

    // ---- layer 2: 64 -> 64 ----
    float c[64];
    #pragma unroll
    for (int j = 0; j < 64; ++j) c[j] = b2[j];
    #pragma unroll
    for (int k = 0; k < 64; ++k) {
        float hv = a[k];
        #pragma unroll
        for (int j = 0; j < 64; ++j) c[j] = fmaf(hv, W2[k*64 + j], c[j]);
    }

    // ---- layer 3 folded into layer-2 consumption: 64 -> 3 + sigmoid ----
    float o0 = b3[0], o1 = b3[1], o2 = b3[2];
    #pragma unroll
    for (int j = 0; j < 64; ++j) {
        float hv = fmaxf(c[j], 0.0f);
        o0 = fmaf(hv, W3[j*3+0], o0);
        o1 = fmaf(hv, W3[j*3+1], o1);
        o2 = fmaf(hv, W3[j*3+2], o2);
    }
    out[3*i+0] = 1.0f / (1.0f + __expf(-o0));
    out[3*i+1] = 1.0f / (1.0f + __expf(-o1));
    out[3*i+2] = 1.0f / (1.0f + __expf(-o2));
}

extern "C" void kernel_launch(void* const* d_in, const int* in_sizes, int n_in,
                              void* d_out, int out_size, void* d_ws, size_t ws_size,
                              hipStream_t stream) {
    const float* pos = (const float*)d_in[0];
    const float* nrm = (const float*)d_in[1];
    const float* emb = (const float*)d_in[2];
    const float* W1  = (const float*)d_in[3];
    const float* b1  = (const float*)d_in[4];
    const float* W2  = (const float*)d_in[5];
    const float* b2  = (const float*)d_in[6];
    const float* W3  = (const float*)d_in[7];
    const float* b3  = (const float*)d_in[8];
    float* out = (float*)d_out;

    int n = in_sizes[0] / 3;   // 4,194,304 points
    int block = 256;
    int grid = (n + block - 1) / block;
    nc_kernel<<<grid, block, 0, stream>>>(pos, nrm, emb, W1, b1, W2, b2, W3, b3, out, n);
}

// Round 2
// 281.463 us; speedup vs baseline: 2.1878x; 2.1878x over previous
//
#include <hip/hip_runtime.h>
#include <hip/hip_bf16.h>
#include <math.h>

// NeuralCache, all-MFMA transposed formulation (zero LDS, zero shuffles).
//
// Every layer computed transposed: h^T = W^T · x^T with v_mfma_f32_16x16x16_bf16.
//   A-operand: A[row=lane&15][k=quad*4+j]   (row = hidden dim, preloaded weights)
//   B-operand: B[k=quad*4+j][col=lane&15]   (col = point index m)
//   C/D:       D[row=quad*4+r][col=lane&15] (verified m89 layout)
// => layer-L output frag nt IS layer-(L+1)'s B-frag for K-step nt (after relu+pack).
// b1 folded into W1 via x[k=19]=1.0; logits computed transposed so lanes 0-15
// hold all 3 output channels of their point.

typedef __attribute__((ext_vector_type(4))) short short4v;
typedef __attribute__((ext_vector_type(4))) float float4v;

static __device__ __forceinline__ short bf16s(float f) {
    __hip_bfloat16 h = __float2bfloat16(f);
    return *reinterpret_cast<short*>(&h);
}
static __device__ __forceinline__ short4v pack4(float a, float b, float c, float d) {
    short4v v;
    v.x = bf16s(a); v.y = bf16s(b); v.z = bf16s(c); v.w = bf16s(d);
    return v;
}
static __device__ __forceinline__ short4v relu_pack(float4v h) {
    return pack4(fmaxf(h.x, 0.f), fmaxf(h.y, 0.f), fmaxf(h.z, 0.f), fmaxf(h.w, 0.f));
}

#define MFMA16(A, B, C) __builtin_amdgcn_mfma_f32_16x16x16bf16_1k((A), (B), (C), 0, 0, 0)

__global__ __launch_bounds__(256, 3) void nc_mfma(
    const float* __restrict__ pos, const float* __restrict__ nrm,
    const float* __restrict__ emb, const float* __restrict__ W1,
    const float* __restrict__ b1, const float* __restrict__ W2,
    const float* __restrict__ b2, const float* __restrict__ W3,
    const float* __restrict__ b3, float* __restrict__ out, int npts)
{
    const int lane = threadIdx.x & 63;
    const int m    = lane & 15;   // point column / weight row (n_loc)
    const int quad = lane >> 4;   // k-chunk

    // ---------------- preload weight A-fragments (once per wave) ----------------
    // L1: A[n][k] = W1[k][n] for k<19, b1[n] at k=19, 0 for k in [20,32)
    short4v w1f[2][4];
    #pragma unroll
    for (int nt = 0; nt < 4; ++nt) {
        const int n  = nt * 16 + m;
        const int k0 = quad * 4;
        w1f[0][nt] = pack4(W1[(k0+0)*64+n], W1[(k0+1)*64+n],
                           W1[(k0+2)*64+n], W1[(k0+3)*64+n]);
        float a = 0.f, b = 0.f, c = 0.f, d = 0.f;
        if (quad == 0) { a = W1[16*64+n]; b = W1[17*64+n]; c = W1[18*64+n]; d = b1[n]; }
        w1f[1][nt] = pack4(a, b, c, d);
    }
    // L2: A[n][k] = W2[k][n], 4 K-steps x 4 N-tiles
    short4v w2f[4][4];
    #pragma unroll
    for (int kt = 0; kt < 4; ++kt) {
        #pragma unroll
        for (int nt = 0; nt < 4; ++nt) {
            const int n  = nt * 16 + m;
            const int k0 = kt * 16 + quad * 4;
            w2f[kt][nt] = pack4(W2[(k0+0)*64+n], W2[(k0+1)*64+n],
                                W2[(k0+2)*64+n], W2[(k0+3)*64+n]);
        }
    }
    // L3: A[c][k] = W3[k][c] for c<3 else 0
    short4v w3f[4];
    #pragma unroll
    for (int kt = 0; kt < 4; ++kt) {
        const int k0 = kt * 16 + quad * 4;
        float a = 0.f, b = 0.f, c = 0.f, d = 0.f;
        if (m < 3) { a = W3[(k0+0)*3+m]; b = W3[(k0+1)*3+m];
                     c = W3[(k0+2)*3+m]; d = W3[(k0+3)*3+m]; }
        w3f[kt] = pack4(a, b, c, d);
    }
    // bias C-init fragments: C[row=quad*4+r][col=m]
    float4v b2v[4];
    #pragma unroll
    for (int nt = 0; nt < 4; ++nt) {
        const int base = nt * 16 + quad * 4;
        float4v v; v.x = b2[base]; v.y = b2[base+1]; v.z = b2[base+2]; v.w = b2[base+3];
        b2v[nt] = v;
    }
    float4v b3v;
    b3v.x = (quad == 0) ? b3[0] : 0.f;
    b3v.y = (quad == 0) ? b3[1] : 0.f;
    b3v.z = (quad == 0) ? b3[2] : 0.f;
    b3v.w = 0.f;

    const float4v zero4 = {0.f, 0.f, 0.f, 0.f};
    const int tilesTotal = npts >> 4;
    const int waveId   = blockIdx.x * 4 + (threadIdx.x >> 6);
    const int numWaves = gridDim.x * 4;

    for (int t = waveId; t < tilesTotal; t += numWaves) {
        const int pt = t * 16 + m;     // this lane's point

        // ---- hash (every lane computes for its column's point) ----
        const float p0 = pos[3*pt+0], p1 = pos[3*pt+1], p2 = pos[3*pt+2];
        const int sx = (int)(p0 * 10.0f);
        const int sy = (int)(p1 * 10.0f);
        const int sz = (int)(p2 * 10.0f);
        const unsigned h = ((unsigned)sx * 73856093u)
                         ^ ((unsigned)sy * 19349663u)
                         ^ ((unsigned)sz * 83492791u);
        const int idx = (int)(h & 4095u);

        // ---- x^T B-fragments ----
        // kt=0: k=quad*4+j -> emb[idx][quad*4 .. +3], one float4 per lane
        const float4* e4 = (const float4*)(emb) + (idx * 4 + quad);
        const float4 e = *e4;
        const short4v xf0 = pack4(e.x, e.y, e.z, e.w);
        // kt=1: quad0 holds k=16..19 = (n0,n1,n2,1.0); quads 1-3 are zero pad
        short4v xf1 = (short4v){0, 0, 0, 0};
        if (quad == 0) {
            const float n0 = nrm[3*pt+0], n1 = nrm[3*pt+1], n2 = nrm[3*pt+2];
            xf1 = pack4(n0, n1, n2, 1.0f);
        }

        // ---- layer 1: h1^T[64x16] ----
        float4v h1[4];
        #pragma unroll
        for (int nt = 0; nt < 4; ++nt) {
            float4v acc = MFMA16(w1f[0][nt], xf0, zero4);
            h1[nt] = MFMA16(w1f[1][nt], xf1, acc);
        }
        short4v pk1[4];
        #pragma unroll
        for (int kt = 0; kt < 4; ++kt) pk1[kt] = relu_pack(h1[kt]);

        // ---- layer 2: h2^T[64x16] ----
        float4v h2[4];
        #pragma unroll
        for (int nt = 0; nt < 4; ++nt) {
            float4v acc = b2v[nt];
            #pragma unroll
            for (int kt = 0; kt < 4; ++kt) acc = MFMA16(w2f[kt][nt], pk1[kt], acc);
            h2[nt] = acc;
        }
        short4v pk2[4];
        #pragma unroll
        for (int kt = 0; kt < 4; ++kt) pk2[kt] = relu_pack(h2[kt]);

        // ---- layer 3: logit^T[16x16] (rows 0..2 valid) ----
        float4v lg = b3v;
        #pragma unroll
        for (int kt = 0; kt < 4; ++kt) lg = MFMA16(w3f[kt], pk2[kt], lg);

        // ---- sigmoid + store: lanes 0-15 hold channels 0..2 of point m in regs x,y,z
        if (quad == 0) {
            const float s0 = 1.0f / (1.0f + __expf(-lg.x));
            const float s1 = 1.0f / (1.0f + __expf(-lg.y));
            const float s2 = 1.0f / (1.0f + __expf(-lg.z));
            float* o = out + 3 * pt;
            o[0] = s0; o[1] = s1; o[2] = s2;
        }
    }
}

extern "C" void kernel_launch(void* const* d_in, const int* in_sizes, int n_in,
                              void* d_out, int out_size, void* d_ws, size_t ws_size,
                              hipStream_t stream) {
    const float* pos = (const float*)d_in[0];
    const float* nrm = (const float*)d_in[1];
    const float* emb = (const float*)d_in[2];
    const float* W1  = (const float*)d_in[3];
    const float* b1  = (const float*)d_in[4];
    const float* W2  = (const float*)d_in[5];
    const float* b2  = (const float*)d_in[6];
    const float* W3  = (const float*)d_in[7];
    const float* b3  = (const float*)d_in[8];
    float* out = (float*)d_out;

    const int npts = in_sizes[0] / 3;   // 4,194,304
    // 768 blocks * 4 waves = 3072 waves; at ~160 VGPR -> 3 waves/SIMD -> all
    // resident in one round (grid-stride loop handles the ragged remainder).
    nc_mfma<<<768, 256, 0, stream>>>(pos, nrm, emb, W1, b1, W2, b2, W3, b3, out, npts);
}